// Round 10
// baseline (304.840 us; speedup 1.0000x reference)
//
#include <hip/hip_runtime.h>
#include <math.h>

// GCN 2-layer: out = A_norm @ relu(A_norm @ x @ W1 + b1) @ W2 + b2
// A_norm = D_dst^{-1/2} (A + I) D_src^{-1/2}
// Structure:
//   - FULL-RANGE degree histograms in 100KB LDS (gfx950: 160KB/CU), packed
//     ushort, no global atomics, single pass over each edge array.
//   - Fused reduce: partial sums -> cnt_dst/isqrts/local scan + per-histblock
//     exclusive prefix; scan_apply re-scans chunk sums per block (fused).
//   - k_fill_rank: CSR fill with LDS-only ranking, full range, single pass.
//   - Gathers on BF16 rows (256B), fp32 accumulate; scales folded in. The
//     gathers sit at the ~3 TB/s random-line service ceiling (rounds 4-8);
//     XCD slicing (r5) and src-range bucketing were analyzed and rejected.
//   - GEMMs: bf16 A (exact) x split-bf16 W (hi/lo) = 2 MFMA products.
//   - k_prep: weight packing + feature conversion in one dispatch.

constexpr int IN_DIM  = 128;
constexpr int HID_DIM = 256;
constexpr int OUT_DIM = 128;

constexpr int NBINS  = 50176;        // >= N, = 49*1024 (aligns with scan chunks)
constexpr int NWORDS = NBINS / 2;    // packed ushort words (25088 -> 100,352 B LDS)
constexpr int HIST_G = 32;           // chunks per edge array (E=800k -> 25k/chunk)

#define DIV_UP(a, b) (((a) + (b) - 1) / (b))

typedef __attribute__((ext_vector_type(8))) short bf16x8;
typedef __attribute__((ext_vector_type(4))) float f32x4;

__device__ __forceinline__ unsigned short f2bf_rtn(float v) {
    unsigned u = __builtin_bit_cast(unsigned, v);
    u += 0x7FFFu + ((u >> 16) & 1u);
    return (unsigned short)(u >> 16);
}
__device__ __forceinline__ unsigned pack2bf(float lo, float hi) {
    return (unsigned)f2bf_rtn(lo) | ((unsigned)f2bf_rtn(hi) << 16);
}

// ---- full-range privatized histogram: grid (HIST_G, 2); y = arr ----
__global__ __launch_bounds__(256) void k_hist(const int* __restrict__ ei, int E,
                                              unsigned* __restrict__ partials) {
    __shared__ unsigned h32[NWORDS];  // 100,352 B, packed 2x ushort, full node range
    const int tid = threadIdx.x;
    const int g = blockIdx.x, arr = blockIdx.y;
    const int* edges = ei + (size_t)arr * E;

    for (int i = tid; i < NWORDS; i += 256) h32[i] = 0;
    __syncthreads();

    const int chunk = DIV_UP(E, HIST_G);
    const int beg = g * chunk;
    const int end = min(beg + chunk, E);
    for (int base = beg + tid * 4; base < end; base += 256 * 4) {
        if (base + 3 < end) {
            int4 v = *reinterpret_cast<const int4*>(edges + base);
            atomicAdd(&h32[v.x >> 1], 1u << ((v.x & 1) << 4));
            atomicAdd(&h32[v.y >> 1], 1u << ((v.y & 1) << 4));
            atomicAdd(&h32[v.z >> 1], 1u << ((v.z & 1) << 4));
            atomicAdd(&h32[v.w >> 1], 1u << ((v.w & 1) << 4));
        } else {
            for (int k = base; k < end; ++k) {
                int r = edges[k];
                atomicAdd(&h32[r >> 1], 1u << ((r & 1) << 4));
            }
        }
    }
    __syncthreads();

    unsigned* outp = partials + (size_t)(arr * HIST_G + g) * NWORDS;
    for (int i = tid; i < NWORDS; i += 256) outp[i] = h32[i];
}

// ---- fused reduce + normalizers + local scan + per-g dst prefix ----
// Block b: nodes [b*1024,(b+1)*1024). prefix layout: [g][NWORDS] packed ushort.
__global__ __launch_bounds__(256) void k_reduce_scan(
    const unsigned* __restrict__ partials,
    int* __restrict__ cnt_dst, float* __restrict__ out_isqrt, float* __restrict__ in_isqrt,
    int* __restrict__ scan_loc, int* __restrict__ chunk_sum,
    unsigned* __restrict__ prefix, int n) {
    __shared__ int wsum[4];
    const int tid = threadIdx.x, lane = tid & 63, wid = tid >> 6;
    const int bnode = blockIdx.x * 1024;
    const int w0 = (bnode >> 1) + tid * 2;

    const unsigned* ps = partials;                                   // arr 0 = src
    const unsigned* pd = partials + (size_t)HIST_G * NWORDS;         // arr 1 = dst
    unsigned* pgp = prefix;

    int s0 = 0, s1 = 0, s2 = 0, s3 = 0;
    int d0 = 0, d1 = 0, d2 = 0, d3 = 0;
#pragma unroll 4
    for (int g = 0; g < HIST_G; ++g) {
        unsigned a = ps[(size_t)g * NWORDS + w0];
        unsigned b = ps[(size_t)g * NWORDS + w0 + 1];
        unsigned c = pd[(size_t)g * NWORDS + w0];
        unsigned d = pd[(size_t)g * NWORDS + w0 + 1];
        // exclusive prefix over g (before accumulating this g's counts)
        pgp[(size_t)g * NWORDS + w0]     = (unsigned)(d0 & 0xFFFF) | ((unsigned)(d1 & 0xFFFF) << 16);
        pgp[(size_t)g * NWORDS + w0 + 1] = (unsigned)(d2 & 0xFFFF) | ((unsigned)(d3 & 0xFFFF) << 16);
        s0 += a & 0xFFFF; s1 += a >> 16; s2 += b & 0xFFFF; s3 += b >> 16;
        d0 += c & 0xFFFF; d1 += c >> 16; d2 += d & 0xFFFF; d3 += d >> 16;
    }

    const int n0 = bnode + tid * 4;
    int sc[4] = {s0, s1, s2, s3};
    int dc[4] = {d0, d1, d2, d3};
#pragma unroll
    for (int j = 0; j < 4; ++j) {
        int node = n0 + j;
        if (node < n) {
            cnt_dst[node] = dc[j];
            out_isqrt[node] = rsqrtf((float)(sc[j] + 1));
            in_isqrt[node]  = rsqrtf((float)(dc[j] + 1));
        } else {
            dc[j] = 0;
        }
    }

    // local exclusive scan of dc over the block's 1024 values
    int s = dc[0] + dc[1] + dc[2] + dc[3];
    int x = s;
#pragma unroll
    for (int off = 1; off < 64; off <<= 1) { int t = __shfl_up(x, off); if (lane >= off) x += t; }
    if (lane == 63) wsum[wid] = x;
    __syncthreads();
    int wo = 0;
    for (int w = 0; w < wid; ++w) wo += wsum[w];
    int excl = wo + x - s;
    int run = excl;
#pragma unroll
    for (int j = 0; j < 4; ++j) {
        int node = n0 + j;
        if (node < n) scan_loc[node] = run;
        run += dc[j];
    }
    if (tid == 255) chunk_sum[blockIdx.x] = wo + x;
}

// scan_apply with fused chunk scan: block b == chunk b; wave 0 scans chunk sums.
__global__ __launch_bounds__(256) void k_scan_apply(
    const int* __restrict__ local, const int* __restrict__ chunk_sum,
    int* __restrict__ row_off, int n, int nc) {
    __shared__ int base_s;
    const int tid = threadIdx.x;
    if (tid < 64) {
        int v = (tid < nc) ? chunk_sum[tid] : 0;
        int x = v;
#pragma unroll
        for (int off = 1; off < 64; off <<= 1) { int t = __shfl_up(x, off); if (tid >= off) x += t; }
        if (tid == blockIdx.x) base_s = x - v;  // exclusive prefix at this chunk
    }
    __syncthreads();
    const int add = base_s;
    int i = blockIdx.x * 1024 + tid * 4;
    if (i >= n) return;
    if (i + 3 < n) {
        int4 v = *reinterpret_cast<const int4*>(local + i);
        v.x += add; v.y += add; v.z += add; v.w += add;
        *reinterpret_cast<int4*>(row_off + i) = v;
    } else {
        for (int k = i; k < n; ++k) row_off[k] = local[k] + add;
    }
}

// ---- atomic-free CSR fill: full-range LDS rank + per-g prefix. grid (HIST_G). ----
__global__ __launch_bounds__(256) void k_fill_rank(
    const int* __restrict__ src, const int* __restrict__ dst,
    const int* __restrict__ row_off, const unsigned* __restrict__ prefix,
    int* __restrict__ csr_src, int E) {
    __shared__ unsigned rk[NWORDS];  // 100,352 B
    const int tid = threadIdx.x;
    const int g = blockIdx.x;
    for (int i = tid; i < NWORDS; i += 256) rk[i] = 0;
    __syncthreads();

    const unsigned* pg = prefix + (size_t)g * NWORDS;
    const int chunk = DIV_UP(E, HIST_G);
    const int beg = g * chunk;
    const int end = min(beg + chunk, E);

    auto do_edge = [&](int d, int s) {
        int sh = (d & 1) << 4;
        unsigned old = atomicAdd(&rk[d >> 1], 1u << sh);
        unsigned rank = (old >> sh) & 0xFFFFu;
        unsigned pref = (pg[d >> 1] >> sh) & 0xFFFFu;
        int pos = row_off[d] + (int)pref + (int)rank;
        csr_src[pos] = s;
    };

    for (int base = beg + tid * 4; base < end; base += 256 * 4) {
        if (base + 3 < end) {
            int4 d4 = *reinterpret_cast<const int4*>(dst + base);
            int4 s4 = *reinterpret_cast<const int4*>(src + base);
            do_edge(d4.x, s4.x); do_edge(d4.y, s4.y);
            do_edge(d4.z, s4.z); do_edge(d4.w, s4.w);
        } else {
            for (int k = base; k < end; ++k) do_edge(dst[k], src[k]);
        }
    }
}

// ---- merged weight packing + feature conversion ----
// idx < T1+T2: pack W1/W2 fp32 -> hi/lo bf16 in MFMA-B fragment order.
// else: xb[u][:] = bf16_rtn(oscale[u] * x[u][:]), 8 elems/thread.
__device__ __forceinline__ void pack_one(const float* __restrict__ W, short* __restrict__ hi,
                                         short* __restrict__ lo, int idx, int KT, int N) {
    int j = idx & 7;
    int l = (idx >> 3) & 63;
    int rest = idx >> 9;
    int kt = rest % KT;
    int nt = rest / KT;
    int k = kt * 32 + ((l >> 4) << 3) + j;
    int col = nt * 16 + (l & 15);
    float w = W[(size_t)k * N + col];
    unsigned u = __builtin_bit_cast(unsigned, w);
    hi[idx] = (short)(u >> 16);
    float hif = __builtin_bit_cast(float, u & 0xFFFF0000u);
    lo[idx] = (short)(__builtin_bit_cast(unsigned, w - hif) >> 16);
}

__global__ __launch_bounds__(256) void k_prep(
    const float* __restrict__ W1, const float* __restrict__ W2,
    short* __restrict__ h1, short* __restrict__ l1,
    short* __restrict__ h2, short* __restrict__ l2,
    const float* __restrict__ x, const float* __restrict__ oscale,
    uint4* __restrict__ xb, int n16) {
    const int T1 = IN_DIM * HID_DIM;
    const int T2 = HID_DIM * OUT_DIM;
    int idx = blockIdx.x * blockDim.x + threadIdx.x;
    if (idx < T1) { pack_one(W1, h1, l1, idx, IN_DIM / 32, HID_DIM); return; }
    if (idx < T1 + T2) { pack_one(W2, h2, l2, idx - T1, HID_DIM / 32, OUT_DIM); return; }
    int c = idx - (T1 + T2);
    if (c >= n16) return;
    int row = c >> 4, w = c & 15;
    float s = oscale[row];
    const float4* xp = reinterpret_cast<const float4*>(x + ((size_t)row << 7) + w * 8);
    float4 a = xp[0], b = xp[1];
    uint4 o;
    o.x = pack2bf(a.x * s, a.y * s);
    o.y = pack2bf(a.z * s, a.w * s);
    o.z = pack2bf(b.x * s, b.y * s);
    o.w = pack2bf(b.z * s, b.w * s);
    xb[c] = o;
}

__device__ __forceinline__ void acc_bf8(float* acc, uint4 v) {
    acc[0] += __builtin_bit_cast(float, v.x << 16);
    acc[1] += __builtin_bit_cast(float, v.x & 0xFFFF0000u);
    acc[2] += __builtin_bit_cast(float, v.y << 16);
    acc[3] += __builtin_bit_cast(float, v.y & 0xFFFF0000u);
    acc[4] += __builtin_bit_cast(float, v.z << 16);
    acc[5] += __builtin_bit_cast(float, v.z & 0xFFFF0000u);
    acc[6] += __builtin_bit_cast(float, v.w << 16);
    acc[7] += __builtin_bit_cast(float, v.w & 0xFFFF0000u);
}

// bf16 gather: wave per node; quarter-wave (16 lanes x 16B) = one 256B row.
// out[v][:] = oscale[v]*(Σ_{u in N(v)+v} feat[u][:]) (+ bias). fp32 accumulate.
template <bool HAS_BIAS, bool OUT_BF16>
__global__ __launch_bounds__(256) void k_gather_bf16(
    const uint4* __restrict__ feat,  // row = 16 x uint4 (128 bf16)
    const int* __restrict__ row_off, const int* __restrict__ cnt,
    const int* __restrict__ csr_src, const float* __restrict__ oscale,
    const float* __restrict__ bias, void* __restrict__ outv, int n) {
    const int node = blockIdx.x * 4 + (threadIdx.x >> 6);
    const int lane = threadIdx.x & 63;
    if (node >= n) return;
    const int q = lane >> 4, c16 = lane & 15;

    float acc[8] = {};
    const int b = row_off[node];
    const int e2 = b + cnt[node];
    int k = b + q;
    for (; k + 12 < e2; k += 16) {
        int s0 = csr_src[k], s1 = csr_src[k + 4], s2 = csr_src[k + 8], s3 = csr_src[k + 12];
        uint4 v0 = feat[((size_t)s0 << 4) + c16];
        uint4 v1 = feat[((size_t)s1 << 4) + c16];
        uint4 v2 = feat[((size_t)s2 << 4) + c16];
        uint4 v3 = feat[((size_t)s3 << 4) + c16];
        acc_bf8(acc, v0); acc_bf8(acc, v1); acc_bf8(acc, v2); acc_bf8(acc, v3);
    }
    for (; k < e2; k += 4) {
        int s = csr_src[k];
        acc_bf8(acc, feat[((size_t)s << 4) + c16]);
    }
    if (q == 0) acc_bf8(acc, feat[((size_t)node << 4) + c16]);  // self loop

#pragma unroll
    for (int j = 0; j < 8; ++j) {
        acc[j] += __shfl_xor(acc[j], 16);
        acc[j] += __shfl_xor(acc[j], 32);
    }
    if (q == 0) {
        float os = oscale[node];
        if (HAS_BIAS) {
            const float4* bb = reinterpret_cast<const float4*>(bias) + c16 * 2;
            float4 b0 = bb[0], b1 = bb[1];
            acc[0] = acc[0] * os + b0.x; acc[1] = acc[1] * os + b0.y;
            acc[2] = acc[2] * os + b0.z; acc[3] = acc[3] * os + b0.w;
            acc[4] = acc[4] * os + b1.x; acc[5] = acc[5] * os + b1.y;
            acc[6] = acc[6] * os + b1.z; acc[7] = acc[7] * os + b1.w;
        } else {
#pragma unroll
            for (int j = 0; j < 8; ++j) acc[j] *= os;
        }
        if (OUT_BF16) {
            uint4 o;
            o.x = pack2bf(acc[0], acc[1]);
            o.y = pack2bf(acc[2], acc[3]);
            o.z = pack2bf(acc[4], acc[5]);
            o.w = pack2bf(acc[6], acc[7]);
            reinterpret_cast<uint4*>(outv)[((size_t)node << 4) + c16] = o;
        } else {
            float4* op = reinterpret_cast<float4*>((float*)outv + ((size_t)node << 7) + c16 * 8);
            op[0] = make_float4(acc[0], acc[1], acc[2], acc[3]);
            op[1] = make_float4(acc[4], acc[5], acc[6], acc[7]);
        }
    }
}

// C[M x Nc] = epi( A[M x K](bf16) @ W(split hi/lo) ): 2 MFMAs per (kt,ct).
// Block: 256 thr = 4 waves; wave: 16 rows x 128 cols (8 col-tiles of 16x16x32).
template <int KT, bool HAS_BIAS, bool RELU, bool HAS_RSOUT, bool OUT_BF16>
__global__ __launch_bounds__(256) void k_gemm_bf16(
    const unsigned short* __restrict__ A, const short* __restrict__ Bp_hi,
    const short* __restrict__ Bp_lo, const float* __restrict__ bias,
    const float* __restrict__ rs_out, void* __restrict__ Cv, int M, int Nc) {
    const int K = KT * 32;
    const int lane = threadIdx.x & 63;
    const int wave = threadIdx.x >> 6;
    const int row0 = blockIdx.y * 64 + wave * 16;
    const int colt0 = blockIdx.x * 8;

    int arow = row0 + (lane & 15);
    int ar = arow < M ? arow : M - 1;
    const int koff = (lane >> 4) << 3;

    f32x4 acc[8];
#pragma unroll
    for (int t = 0; t < 8; ++t) acc[t] = (f32x4){0.f, 0.f, 0.f, 0.f};

    const bf16x8* bh = reinterpret_cast<const bf16x8*>(Bp_hi);
    const bf16x8* bl = reinterpret_cast<const bf16x8*>(Bp_lo);

#pragma unroll
    for (int kt = 0; kt < KT; ++kt) {
        bf16x8 a = *reinterpret_cast<const bf16x8*>(A + (size_t)ar * K + kt * 32 + koff);
#pragma unroll
        for (int ct = 0; ct < 8; ++ct) {
            int bidx = (colt0 + ct) * KT + kt;
            bf16x8 bhv = bh[bidx * 64 + lane];
            bf16x8 blv = bl[bidx * 64 + lane];
            acc[ct] = __builtin_amdgcn_mfma_f32_16x16x32_bf16(a, bhv, acc[ct], 0, 0, 0);
            acc[ct] = __builtin_amdgcn_mfma_f32_16x16x32_bf16(a, blv, acc[ct], 0, 0, 0);
        }
    }

    const int crow0 = row0 + ((lane >> 4) << 2);
    float rso[4];
#pragma unroll
    for (int j = 0; j < 4; ++j)
        rso[j] = HAS_RSOUT ? ((crow0 + j < M) ? rs_out[crow0 + j] : 0.f) : 1.0f;

#pragma unroll
    for (int ct = 0; ct < 8; ++ct) {
        int col = (colt0 + ct) * 16 + (lane & 15);
        float bv = HAS_BIAS ? bias[col] : 0.f;
#pragma unroll
        for (int j = 0; j < 4; ++j) {
            int row = crow0 + j;
            if (row >= M) continue;
            float v = acc[ct][j] + bv;
            if (RELU) v = fmaxf(v, 0.f);
            v *= rso[j];
            if (OUT_BF16)
                ((unsigned short*)Cv)[(size_t)row * Nc + col] = f2bf_rtn(v);
            else
                ((float*)Cv)[(size_t)row * Nc + col] = v;
        }
    }
}

extern "C" void kernel_launch(void* const* d_in, const int* in_sizes, int n_in,
                              void* d_out, int out_size, void* d_ws, size_t ws_size,
                              hipStream_t stream) {
    const float* x  = (const float*)d_in[0];
    const int*   ei = (const int*)d_in[1];
    const float* W1 = (const float*)d_in[2];
    const float* b1 = (const float*)d_in[3];
    const float* W2 = (const float*)d_in[4];
    const float* b2 = (const float*)d_in[5];
    float* out = (float*)d_out;

    const int N = in_sizes[0] / IN_DIM;
    const int E = in_sizes[1] / 2;
    const int* src = ei;
    const int* dst = ei + E;

    char* ws = (char*)d_ws;
    size_t off = 0;
    auto alloc = [&](size_t bytes) {
        void* p = ws + off;
        off += (bytes + 255) & ~(size_t)255;
        return p;
    };
    int*   cnt_dst   = (int*)alloc((size_t)N * sizeof(int));
    float* out_isqrt = (float*)alloc((size_t)N * sizeof(float));
    float* in_isqrt  = (float*)alloc((size_t)N * sizeof(float));
    int*   row_off   = (int*)alloc((size_t)N * sizeof(int));
    int*   scan_loc  = (int*)alloc((size_t)N * sizeof(int));
    int*   chunk_sum = (int*)alloc(64 * sizeof(int));
    int*   csr_src   = (int*)alloc((size_t)E * sizeof(int));
    short* W1p_hi    = (short*)alloc((size_t)IN_DIM * HID_DIM * sizeof(short));
    short* W1p_lo    = (short*)alloc((size_t)IN_DIM * HID_DIM * sizeof(short));
    short* W2p_hi    = (short*)alloc((size_t)HID_DIM * OUT_DIM * sizeof(short));
    short* W2p_lo    = (short*)alloc((size_t)HID_DIM * OUT_DIM * sizeof(short));
    uint4* xb  = (uint4*)alloc((size_t)N * IN_DIM * 2);                        // 12.8 MB bf16
    unsigned short* m1b = (unsigned short*)alloc((size_t)N * IN_DIM * 2);      // 12.8 MB bf16
    unsigned short* h1b = (unsigned short*)alloc((size_t)N * HID_DIM * 2);     // 25.6 MB bf16
    unsigned short* t2b = (unsigned short*)alloc((size_t)N * OUT_DIM * 2);     // 12.8 MB bf16

    // Overlays on h1b (25.6 MB), both dead before k_gemm_bf16 writes h1b:
    //   partials 6.4 MB at offset 0; prefix 3.2 MB right after.
    unsigned* partials = (unsigned*)h1b;
    unsigned* prefix   = (unsigned*)((char*)h1b + (size_t)2 * HIST_G * NWORDS * 4);

    const int thr = 256;
    const int nchunks = DIV_UP(N, 1024);  // 49

    // degrees + normalizers + CSR (no global atomics anywhere)
    k_hist<<<dim3(HIST_G, 2), 256, 0, stream>>>(ei, E, partials);
    k_reduce_scan<<<nchunks, 256, 0, stream>>>(partials, cnt_dst, out_isqrt, in_isqrt,
                                               scan_loc, chunk_sum, prefix, N);
    k_scan_apply<<<nchunks, 256, 0, stream>>>(scan_loc, chunk_sum, row_off, N, nchunks);
    k_fill_rank<<<HIST_G, 256, 0, stream>>>(src, dst, row_off, prefix, csr_src, E);

    // weight packing + feature conversion (one dispatch)
    const int PREP_T = IN_DIM * HID_DIM + HID_DIM * OUT_DIM + N * 16;
    k_prep<<<DIV_UP(PREP_T, thr), thr, 0, stream>>>(
        W1, W2, W1p_hi, W1p_lo, W2p_hi, W2p_lo, x, out_isqrt, xb, N * 16);

    // layer 1: m1b = bf16(in_isqrt ⊙ (A+I) xb); h1b = bf16(relu(m1b@W1 + b1))
    k_gather_bf16<false, true><<<DIV_UP(N, 4), 256, 0, stream>>>(
        xb, row_off, cnt_dst, csr_src, in_isqrt, nullptr, m1b, N);
    k_gemm_bf16<IN_DIM / 32, true, true, false, true>
        <<<dim3(HID_DIM / 128, DIV_UP(N, 64)), 256, 0, stream>>>(
            m1b, W1p_hi, W1p_lo, b1, nullptr, h1b, N, HID_DIM);

    // layer 2: t2b = bf16(out_isqrt ⊙ (h1b@W2)); out = in_isqrt ⊙ ((A+I) t2b) + b2
    k_gemm_bf16<HID_DIM / 32, false, false, true, true>
        <<<dim3(OUT_DIM / 128, DIV_UP(N, 64)), 256, 0, stream>>>(
            h1b, W2p_hi, W2p_lo, nullptr, out_isqrt, t2b, N, OUT_DIM);
    k_gather_bf16<true, false><<<DIV_UP(N, 4), 256, 0, stream>>>(
        (const uint4*)t2b, row_off, cnt_dst, csr_src, in_isqrt, b2, out, N);
}

// Round 12
// 264.658 us; speedup vs baseline: 1.1518x; 1.1518x over previous
//
#include <hip/hip_runtime.h>
#include <math.h>

// GCN 2-layer: out = A_norm @ relu(A_norm @ x @ W1 + b1) @ W2 + b2
// A_norm = D_dst^{-1/2} (A + I) D_src^{-1/2}
// Structure (round-9 CSR build restored; round-10 full-range LDS hist REVERTED:
// 100KB LDS -> 1 block/CU, 32 blocks total = 1.2% occupancy, fill 20->69us):
//   - Half-split degree histograms (51.2KB LDS, 3 blocks/CU) via LDS
//     privatization, packed ushort, no global atomics.
//   - Fused reduce: partial sums -> cnt_dst/isqrts/local scan + per-histblock
//     exclusive prefix; scan_apply re-scans chunk sums per block (fused).
//   - k_fill_rank: CSR fill with LDS-only ranking (pos = row_off+prefix+rank).
//   - Gathers on BF16 rows (256B), fp32 accumulate; scales folded in. The
//     gathers sit at the ~3 TB/s random-line service ceiling (rounds 4-8);
//     XCD slicing (r5) and src-range bucketing were analyzed and rejected.
//   - GEMMs: bf16 A (exact) x split-bf16 W (hi/lo) = 2 MFMA products.
//   - k_prep: weight packing + feature conversion in one dispatch.
// (Round-11 submission was not measured: GPUAcquisitionTimeout. Resubmitting.)

constexpr int IN_DIM  = 128;
constexpr int HID_DIM = 256;
constexpr int OUT_DIM = 128;

constexpr int HALF_BINS = 25600;          // node-range half (25600*2 >= N), % 1024 == 0
constexpr int HWORDS    = HALF_BINS / 2;  // packed ushort words (51.2 KB LDS)
constexpr int HIST_G    = 64;             // blocks per (array, half)

#define DIV_UP(a, b) (((a) + (b) - 1) / (b))

typedef __attribute__((ext_vector_type(8))) short bf16x8;
typedef __attribute__((ext_vector_type(4))) float f32x4;

__device__ __forceinline__ unsigned short f2bf_rtn(float v) {
    unsigned u = __builtin_bit_cast(unsigned, v);
    u += 0x7FFFu + ((u >> 16) & 1u);
    return (unsigned short)(u >> 16);
}
__device__ __forceinline__ unsigned pack2bf(float lo, float hi) {
    return (unsigned)f2bf_rtn(lo) | ((unsigned)f2bf_rtn(hi) << 16);
}

// ---- privatized degree histogram: grid (HIST_G, 4); y = half*2 + arr ----
__global__ __launch_bounds__(256) void k_hist(const int* __restrict__ ei, int E,
                                              unsigned* __restrict__ partials) {
    __shared__ unsigned h32[HWORDS];  // 51200 B, packed 2x ushort
    const int tid = threadIdx.x;
    const int g = blockIdx.x;
    const int arr = blockIdx.y & 1, half = blockIdx.y >> 1;
    const int lo = half * HALF_BINS;
    const int* edges = ei + (size_t)arr * E;

    for (int i = tid; i < HWORDS; i += 256) h32[i] = 0;
    __syncthreads();

    const int chunk = DIV_UP(E, HIST_G);
    const int beg = g * chunk;
    const int end = min(beg + chunk, E);
    for (int base = beg + tid * 4; base < end; base += 256 * 4) {
        if (base + 3 < end) {
            int4 v = *reinterpret_cast<const int4*>(edges + base);
            int r;
            r = v.x - lo; if ((unsigned)r < HALF_BINS) atomicAdd(&h32[r >> 1], 1u << ((r & 1) << 4));
            r = v.y - lo; if ((unsigned)r < HALF_BINS) atomicAdd(&h32[r >> 1], 1u << ((r & 1) << 4));
            r = v.z - lo; if ((unsigned)r < HALF_BINS) atomicAdd(&h32[r >> 1], 1u << ((r & 1) << 4));
            r = v.w - lo; if ((unsigned)r < HALF_BINS) atomicAdd(&h32[r >> 1], 1u << ((r & 1) << 4));
        } else {
            for (int k = base; k < end; ++k) {
                int r = edges[k] - lo;
                if ((unsigned)r < HALF_BINS) atomicAdd(&h32[r >> 1], 1u << ((r & 1) << 4));
            }
        }
    }
    __syncthreads();

    unsigned* outp = partials + (size_t)(blockIdx.y * HIST_G + g) * HWORDS;
    for (int i = tid; i < HWORDS; i += 256) outp[i] = h32[i];
}

// ---- fused reduce + normalizers + local scan + per-g dst prefix ----
// Block b: nodes [b*1024,(b+1)*1024). prefix layout: [half][g][HWORDS] packed ushort.
__global__ __launch_bounds__(256) void k_reduce_scan(
    const unsigned* __restrict__ partials,
    int* __restrict__ cnt_dst, float* __restrict__ out_isqrt, float* __restrict__ in_isqrt,
    int* __restrict__ scan_loc, int* __restrict__ chunk_sum,
    unsigned* __restrict__ prefix, int n) {
    __shared__ int wsum[4];
    const int tid = threadIdx.x, lane = tid & 63, wid = tid >> 6;
    const int bnode = blockIdx.x * 1024;
    const int half = (bnode >= HALF_BINS) ? 1 : 0;  // HALF_BINS % 1024 == 0, no straddle
    const int w0 = ((bnode - half * HALF_BINS) >> 1) + tid * 2;

    const unsigned* ps = partials + (size_t)(2 * half + 0) * HIST_G * HWORDS;
    const unsigned* pd = partials + (size_t)(2 * half + 1) * HIST_G * HWORDS;
    unsigned* pgp = prefix + (size_t)half * HIST_G * HWORDS;

    int s0 = 0, s1 = 0, s2 = 0, s3 = 0;
    int d0 = 0, d1 = 0, d2 = 0, d3 = 0;
#pragma unroll 4
    for (int g = 0; g < HIST_G; ++g) {
        unsigned a = ps[(size_t)g * HWORDS + w0];
        unsigned b = ps[(size_t)g * HWORDS + w0 + 1];
        unsigned c = pd[(size_t)g * HWORDS + w0];
        unsigned d = pd[(size_t)g * HWORDS + w0 + 1];
        // exclusive prefix over g (before accumulating this g's counts)
        pgp[(size_t)g * HWORDS + w0]     = (unsigned)(d0 & 0xFFFF) | ((unsigned)(d1 & 0xFFFF) << 16);
        pgp[(size_t)g * HWORDS + w0 + 1] = (unsigned)(d2 & 0xFFFF) | ((unsigned)(d3 & 0xFFFF) << 16);
        s0 += a & 0xFFFF; s1 += a >> 16; s2 += b & 0xFFFF; s3 += b >> 16;
        d0 += c & 0xFFFF; d1 += c >> 16; d2 += d & 0xFFFF; d3 += d >> 16;
    }

    const int n0 = bnode + tid * 4;
    int sc[4] = {s0, s1, s2, s3};
    int dc[4] = {d0, d1, d2, d3};
#pragma unroll
    for (int j = 0; j < 4; ++j) {
        int node = n0 + j;
        if (node < n) {
            cnt_dst[node] = dc[j];
            out_isqrt[node] = rsqrtf((float)(sc[j] + 1));
            in_isqrt[node]  = rsqrtf((float)(dc[j] + 1));
        } else {
            dc[j] = 0;
        }
    }

    // local exclusive scan of dc over the block's 1024 values
    int s = dc[0] + dc[1] + dc[2] + dc[3];
    int x = s;
#pragma unroll
    for (int off = 1; off < 64; off <<= 1) { int t = __shfl_up(x, off); if (lane >= off) x += t; }
    if (lane == 63) wsum[wid] = x;
    __syncthreads();
    int wo = 0;
    for (int w = 0; w < wid; ++w) wo += wsum[w];
    int excl = wo + x - s;
    int run = excl;
#pragma unroll
    for (int j = 0; j < 4; ++j) {
        int node = n0 + j;
        if (node < n) scan_loc[node] = run;
        run += dc[j];
    }
    if (tid == 255) chunk_sum[blockIdx.x] = wo + x;
}

// scan_apply with fused chunk scan: block b == chunk b; wave 0 scans chunk sums.
__global__ __launch_bounds__(256) void k_scan_apply(
    const int* __restrict__ local, const int* __restrict__ chunk_sum,
    int* __restrict__ row_off, int n, int nc) {
    __shared__ int base_s;
    const int tid = threadIdx.x;
    if (tid < 64) {
        int v = (tid < nc) ? chunk_sum[tid] : 0;
        int x = v;
#pragma unroll
        for (int off = 1; off < 64; off <<= 1) { int t = __shfl_up(x, off); if (tid >= off) x += t; }
        if (tid == blockIdx.x) base_s = x - v;  // exclusive prefix at this chunk
    }
    __syncthreads();
    const int add = base_s;
    int i = blockIdx.x * 1024 + tid * 4;
    if (i >= n) return;
    if (i + 3 < n) {
        int4 v = *reinterpret_cast<const int4*>(local + i);
        v.x += add; v.y += add; v.z += add; v.w += add;
        *reinterpret_cast<int4*>(row_off + i) = v;
    } else {
        for (int k = i; k < n; ++k) row_off[k] = local[k] + add;
    }
}

// ---- atomic-free CSR fill: LDS rank + per-g prefix. grid (HIST_G, 2). ----
__global__ __launch_bounds__(256) void k_fill_rank(
    const int* __restrict__ src, const int* __restrict__ dst,
    const int* __restrict__ row_off, const unsigned* __restrict__ prefix,
    int* __restrict__ csr_src, int E) {
    __shared__ unsigned rk[HWORDS];  // 51.2 KB
    const int tid = threadIdx.x;
    const int g = blockIdx.x, half = blockIdx.y;
    const int lo = half * HALF_BINS;
    for (int i = tid; i < HWORDS; i += 256) rk[i] = 0;
    __syncthreads();

    const unsigned* pg = prefix + (size_t)(half * HIST_G + g) * HWORDS;
    const int chunk = DIV_UP(E, HIST_G);
    const int beg = g * chunk;
    const int end = min(beg + chunk, E);

    auto do_edge = [&](int d, int s) {
        int r = d - lo;
        if ((unsigned)r < HALF_BINS) {
            int sh = (r & 1) << 4;
            unsigned old = atomicAdd(&rk[r >> 1], 1u << sh);
            unsigned rank = (old >> sh) & 0xFFFFu;
            unsigned pref = (pg[r >> 1] >> sh) & 0xFFFFu;
            int pos = row_off[d] + (int)pref + (int)rank;
            csr_src[pos] = s;
        }
    };

    for (int base = beg + tid * 4; base < end; base += 256 * 4) {
        if (base + 3 < end) {
            int4 d4 = *reinterpret_cast<const int4*>(dst + base);
            int4 s4 = *reinterpret_cast<const int4*>(src + base);
            do_edge(d4.x, s4.x); do_edge(d4.y, s4.y);
            do_edge(d4.z, s4.z); do_edge(d4.w, s4.w);
        } else {
            for (int k = base; k < end; ++k) do_edge(dst[k], src[k]);
        }
    }
}

// ---- merged weight packing + feature conversion ----
__device__ __forceinline__ void pack_one(const float* __restrict__ W, short* __restrict__ hi,
                                         short* __restrict__ lo, int idx, int KT, int N) {
    int j = idx & 7;
    int l = (idx >> 3) & 63;
    int rest = idx >> 9;
    int kt = rest % KT;
    int nt = rest / KT;
    int k = kt * 32 + ((l >> 4) << 3) + j;
    int col = nt * 16 + (l & 15);
    float w = W[(size_t)k * N + col];
    unsigned u = __builtin_bit_cast(unsigned, w);
    hi[idx] = (short)(u >> 16);
    float hif = __builtin_bit_cast(float, u & 0xFFFF0000u);
    lo[idx] = (short)(__builtin_bit_cast(unsigned, w - hif) >> 16);
}

__global__ __launch_bounds__(256) void k_prep(
    const float* __restrict__ W1, const float* __restrict__ W2,
    short* __restrict__ h1, short* __restrict__ l1,
    short* __restrict__ h2, short* __restrict__ l2,
    const float* __restrict__ x, const float* __restrict__ oscale,
    uint4* __restrict__ xb, int n16) {
    const int T1 = IN_DIM * HID_DIM;
    const int T2 = HID_DIM * OUT_DIM;
    int idx = blockIdx.x * blockDim.x + threadIdx.x;
    if (idx < T1) { pack_one(W1, h1, l1, idx, IN_DIM / 32, HID_DIM); return; }
    if (idx < T1 + T2) { pack_one(W2, h2, l2, idx - T1, HID_DIM / 32, OUT_DIM); return; }
    int c = idx - (T1 + T2);
    if (c >= n16) return;
    int row = c >> 4, w = c & 15;
    float s = oscale[row];
    const float4* xp = reinterpret_cast<const float4*>(x + ((size_t)row << 7) + w * 8);
    float4 a = xp[0], b = xp[1];
    uint4 o;
    o.x = pack2bf(a.x * s, a.y * s);
    o.y = pack2bf(a.z * s, a.w * s);
    o.z = pack2bf(b.x * s, b.y * s);
    o.w = pack2bf(b.z * s, b.w * s);
    xb[c] = o;
}

__device__ __forceinline__ void acc_bf8(float* acc, uint4 v) {
    acc[0] += __builtin_bit_cast(float, v.x << 16);
    acc[1] += __builtin_bit_cast(float, v.x & 0xFFFF0000u);
    acc[2] += __builtin_bit_cast(float, v.y << 16);
    acc[3] += __builtin_bit_cast(float, v.y & 0xFFFF0000u);
    acc[4] += __builtin_bit_cast(float, v.z << 16);
    acc[5] += __builtin_bit_cast(float, v.z & 0xFFFF0000u);
    acc[6] += __builtin_bit_cast(float, v.w << 16);
    acc[7] += __builtin_bit_cast(float, v.w & 0xFFFF0000u);
}

// bf16 gather: wave per node; quarter-wave (16 lanes x 16B) = one 256B row.
// out[v][:] = oscale[v]*(Σ_{u in N(v)+v} feat[u][:]) (+ bias). fp32 accumulate.
template <bool HAS_BIAS, bool OUT_BF16>
__global__ __launch_bounds__(256) void k_gather_bf16(
    const uint4* __restrict__ feat,  // row = 16 x uint4 (128 bf16)
    const int* __restrict__ row_off, const int* __restrict__ cnt,
    const int* __restrict__ csr_src, const float* __restrict__ oscale,
    const float* __restrict__ bias, void* __restrict__ outv, int n) {
    const int node = blockIdx.x * 4 + (threadIdx.x >> 6);
    const int lane = threadIdx.x & 63;
    if (node >= n) return;
    const int q = lane >> 4, c16 = lane & 15;

    float acc[8] = {};
    const int b = row_off[node];
    const int e2 = b + cnt[node];
    int k = b + q;
    for (; k + 12 < e2; k += 16) {
        int s0 = csr_src[k], s1 = csr_src[k + 4], s2 = csr_src[k + 8], s3 = csr_src[k + 12];
        uint4 v0 = feat[((size_t)s0 << 4) + c16];
        uint4 v1 = feat[((size_t)s1 << 4) + c16];
        uint4 v2 = feat[((size_t)s2 << 4) + c16];
        uint4 v3 = feat[((size_t)s3 << 4) + c16];
        acc_bf8(acc, v0); acc_bf8(acc, v1); acc_bf8(acc, v2); acc_bf8(acc, v3);
    }
    for (; k < e2; k += 4) {
        int s = csr_src[k];
        acc_bf8(acc, feat[((size_t)s << 4) + c16]);
    }
    if (q == 0) acc_bf8(acc, feat[((size_t)node << 4) + c16]);  // self loop

#pragma unroll
    for (int j = 0; j < 8; ++j) {
        acc[j] += __shfl_xor(acc[j], 16);
        acc[j] += __shfl_xor(acc[j], 32);
    }
    if (q == 0) {
        float os = oscale[node];
        if (HAS_BIAS) {
            const float4* bb = reinterpret_cast<const float4*>(bias) + c16 * 2;
            float4 b0 = bb[0], b1 = bb[1];
            acc[0] = acc[0] * os + b0.x; acc[1] = acc[1] * os + b0.y;
            acc[2] = acc[2] * os + b0.z; acc[3] = acc[3] * os + b0.w;
            acc[4] = acc[4] * os + b1.x; acc[5] = acc[5] * os + b1.y;
            acc[6] = acc[6] * os + b1.z; acc[7] = acc[7] * os + b1.w;
        } else {
#pragma unroll
            for (int j = 0; j < 8; ++j) acc[j] *= os;
        }
        if (OUT_BF16) {
            uint4 o;
            o.x = pack2bf(acc[0], acc[1]);
            o.y = pack2bf(acc[2], acc[3]);
            o.z = pack2bf(acc[4], acc[5]);
            o.w = pack2bf(acc[6], acc[7]);
            reinterpret_cast<uint4*>(outv)[((size_t)node << 4) + c16] = o;
        } else {
            float4* op = reinterpret_cast<float4*>((float*)outv + ((size_t)node << 7) + c16 * 8);
            op[0] = make_float4(acc[0], acc[1], acc[2], acc[3]);
            op[1] = make_float4(acc[4], acc[5], acc[6], acc[7]);
        }
    }
}

// C[M x Nc] = epi( A[M x K](bf16) @ W(split hi/lo) ): 2 MFMAs per (kt,ct).
// Block: 256 thr = 4 waves; wave: 16 rows x 128 cols (8 col-tiles of 16x16x32).
template <int KT, bool HAS_BIAS, bool RELU, bool HAS_RSOUT, bool OUT_BF16>
__global__ __launch_bounds__(256) void k_gemm_bf16(
    const unsigned short* __restrict__ A, const short* __restrict__ Bp_hi,
    const short* __restrict__ Bp_lo, const float* __restrict__ bias,
    const float* __restrict__ rs_out, void* __restrict__ Cv, int M, int Nc) {
    const int K = KT * 32;
    const int lane = threadIdx.x & 63;
    const int wave = threadIdx.x >> 6;
    const int row0 = blockIdx.y * 64 + wave * 16;
    const int colt0 = blockIdx.x * 8;

    int arow = row0 + (lane & 15);
    int ar = arow < M ? arow : M - 1;
    const int koff = (lane >> 4) << 3;

    f32x4 acc[8];
#pragma unroll
    for (int t = 0; t < 8; ++t) acc[t] = (f32x4){0.f, 0.f, 0.f, 0.f};

    const bf16x8* bh = reinterpret_cast<const bf16x8*>(Bp_hi);
    const bf16x8* bl = reinterpret_cast<const bf16x8*>(Bp_lo);

#pragma unroll
    for (int kt = 0; kt < KT; ++kt) {
        bf16x8 a = *reinterpret_cast<const bf16x8*>(A + (size_t)ar * K + kt * 32 + koff);
#pragma unroll
        for (int ct = 0; ct < 8; ++ct) {
            int bidx = (colt0 + ct) * KT + kt;
            bf16x8 bhv = bh[bidx * 64 + lane];
            bf16x8 blv = bl[bidx * 64 + lane];
            acc[ct] = __builtin_amdgcn_mfma_f32_16x16x32_bf16(a, bhv, acc[ct], 0, 0, 0);
            acc[ct] = __builtin_amdgcn_mfma_f32_16x16x32_bf16(a, blv, acc[ct], 0, 0, 0);
        }
    }

    const int crow0 = row0 + ((lane >> 4) << 2);
    float rso[4];
#pragma unroll
    for (int j = 0; j < 4; ++j)
        rso[j] = HAS_RSOUT ? ((crow0 + j < M) ? rs_out[crow0 + j] : 0.f) : 1.0f;

#pragma unroll
    for (int ct = 0; ct < 8; ++ct) {
        int col = (colt0 + ct) * 16 + (lane & 15);
        float bv = HAS_BIAS ? bias[col] : 0.f;
#pragma unroll
        for (int j = 0; j < 4; ++j) {
            int row = crow0 + j;
            if (row >= M) continue;
            float v = acc[ct][j] + bv;
            if (RELU) v = fmaxf(v, 0.f);
            v *= rso[j];
            if (OUT_BF16)
                ((unsigned short*)Cv)[(size_t)row * Nc + col] = f2bf_rtn(v);
            else
                ((float*)Cv)[(size_t)row * Nc + col] = v;
        }
    }
}

extern "C" void kernel_launch(void* const* d_in, const int* in_sizes, int n_in,
                              void* d_out, int out_size, void* d_ws, size_t ws_size,
                              hipStream_t stream) {
    const float* x  = (const float*)d_in[0];
    const int*   ei = (const int*)d_in[1];
    const float* W1 = (const float*)d_in[2];
    const float* b1 = (const float*)d_in[3];
    const float* W2 = (const float*)d_in[4];
    const float* b2 = (const float*)d_in[5];
    float* out = (float*)d_out;

    const int N = in_sizes[0] / IN_DIM;
    const int E = in_sizes[1] / 2;
    const int* src = ei;
    const int* dst = ei + E;

    char* ws = (char*)d_ws;
    size_t off = 0;
    auto alloc = [&](size_t bytes) {
        void* p = ws + off;
        off += (bytes + 255) & ~(size_t)255;
        return p;
    };
    int*   cnt_dst   = (int*)alloc((size_t)N * sizeof(int));
    float* out_isqrt = (float*)alloc((size_t)N * sizeof(float));
    float* in_isqrt  = (float*)alloc((size_t)N * sizeof(float));
    int*   row_off   = (int*)alloc((size_t)N * sizeof(int));
    int*   scan_loc  = (int*)alloc((size_t)N * sizeof(int));
    int*   chunk_sum = (int*)alloc(64 * sizeof(int));
    int*   csr_src   = (int*)alloc((size_t)E * sizeof(int));
    short* W1p_hi    = (short*)alloc((size_t)IN_DIM * HID_DIM * sizeof(short));
    short* W1p_lo    = (short*)alloc((size_t)IN_DIM * HID_DIM * sizeof(short));
    short* W2p_hi    = (short*)alloc((size_t)HID_DIM * OUT_DIM * sizeof(short));
    short* W2p_lo    = (short*)alloc((size_t)HID_DIM * OUT_DIM * sizeof(short));
    uint4* xb  = (uint4*)alloc((size_t)N * IN_DIM * 2);                        // 12.8 MB bf16
    unsigned short* m1b = (unsigned short*)alloc((size_t)N * IN_DIM * 2);      // 12.8 MB bf16
    unsigned short* h1b = (unsigned short*)alloc((size_t)N * HID_DIM * 2);     // 25.6 MB bf16
    unsigned short* t2b = (unsigned short*)alloc((size_t)N * OUT_DIM * 2);     // 12.8 MB bf16

    // Overlays on h1b (25.6 MB), both dead before k_gemm_bf16 writes h1b:
    //   partials 13.1 MB at offset 0; prefix 6.6 MB right after.
    unsigned* partials = (unsigned*)h1b;
    unsigned* prefix   = (unsigned*)((char*)h1b + (size_t)4 * HIST_G * HWORDS * 4);

    const int thr = 256;
    const int nchunks = DIV_UP(N, 1024);  // 49

    // degrees + normalizers + CSR (no global atomics anywhere)
    k_hist<<<dim3(HIST_G, 4), 256, 0, stream>>>(ei, E, partials);
    k_reduce_scan<<<nchunks, 256, 0, stream>>>(partials, cnt_dst, out_isqrt, in_isqrt,
                                               scan_loc, chunk_sum, prefix, N);
    k_scan_apply<<<nchunks, 256, 0, stream>>>(scan_loc, chunk_sum, row_off, N, nchunks);
    k_fill_rank<<<dim3(HIST_G, 2), 256, 0, stream>>>(src, dst, row_off, prefix, csr_src, E);

    // weight packing + feature conversion (one dispatch)
    const int PREP_T = IN_DIM * HID_DIM + HID_DIM * OUT_DIM + N * 16;
    k_prep<<<DIV_UP(PREP_T, thr), thr, 0, stream>>>(
        W1, W2, W1p_hi, W1p_lo, W2p_hi, W2p_lo, x, out_isqrt, xb, N * 16);

    // layer 1: m1b = bf16(in_isqrt ⊙ (A+I) xb); h1b = bf16(relu(m1b@W1 + b1))
    k_gather_bf16<false, true><<<DIV_UP(N, 4), 256, 0, stream>>>(
        xb, row_off, cnt_dst, csr_src, in_isqrt, nullptr, m1b, N);
    k_gemm_bf16<IN_DIM / 32, true, true, false, true>
        <<<dim3(HID_DIM / 128, DIV_UP(N, 64)), 256, 0, stream>>>(
            m1b, W1p_hi, W1p_lo, b1, nullptr, h1b, N, HID_DIM);

    // layer 2: t2b = bf16(out_isqrt ⊙ (h1b@W2)); out = in_isqrt ⊙ ((A+I) t2b) + b2
    k_gemm_bf16<HID_DIM / 32, false, false, true, true>
        <<<dim3(OUT_DIM / 128, DIV_UP(N, 64)), 256, 0, stream>>>(
            h1b, W2p_hi, W2p_lo, nullptr, out_isqrt, t2b, N, OUT_DIM);
    k_gather_bf16<true, false><<<DIV_UP(N, 4), 256, 0, stream>>>(
        (const uint4*)t2b, row_off, cnt_dst, csr_src, in_isqrt, b2, out, N);
}